// Round 3
// baseline (228.038 us; speedup 1.0000x reference)
//
#include <hip/hip_runtime.h>

// IDM layer forward: 1M independent elements, 50 Euler steps each,
// output (BATCH, 50) f32 row-major. Write-BW-bound (200 MB out, 12 MB in).
//
// v2b: 1 thread = 1 element, acc[50] in registers (fully unrolled, static
// indexing). Output transpose goes through a DOUBLE-BUFFERED 2x12.8KB LDS:
// four 64-element groups per 256-block; group g+1 stages into one buffer
// while all 256 threads stream group g's buffer to global with coalesced
// nontemporal stores. LDS = 25,600 B/block -> 6 blocks/CU (24 waves/CU,
// 2x the v1 occupancy), and staging overlaps storing.
// (v2 fix: __builtin_nontemporal_store needs a clang ext_vector type, not
// HIP's float4 class.)

namespace {

constexpr int STEPS   = 50;
constexpr int BLOCK   = 256;
constexpr int GROUP   = 64;              // one wave's worth of elements
constexpr int NGROUPS = BLOCK / GROUP;   // 4
constexpr float DT  = 0.1f;
constexpr float EPS = 1e-5f;

typedef float f32x4 __attribute__((ext_vector_type(4)));
typedef float f32x2 __attribute__((ext_vector_type(2)));

__global__ __launch_bounds__(BLOCK, 6) void idm_forward(
    const float* __restrict__ vi_in,
    const float* __restrict__ dv_in,
    const float* __restrict__ dd_in,
    const float* __restrict__ p_vf,
    const float* __restrict__ p_A,
    const float* __restrict__ p_b,
    const float* __restrict__ p_s0,
    const float* __restrict__ p_T,
    float* __restrict__ out,
    int n)
{
    __shared__ __align__(16) float lds[2][GROUP * STEPS];  // 2 x 12800 B

    const int tid  = threadIdx.x;
    const int base = blockIdx.x * BLOCK;
    const int i    = base + tid;

    // Scalar learned params (single-element arrays).
    const float vf = p_vf[0];
    const float A  = p_A[0];
    const float b  = p_b[0];
    const float s0 = p_s0[0];
    const float T  = p_T[0];
    const float inv2   = 1.0f / (2.0f * sqrtf(A * b));   // 1/(2*sqrt(A*b))
    const float inv_vf = 1.0f / vf;

    float v = 0.0f, dv = 0.0f, inv_dd = 1.0f;
    if (i < n) {
        v      = vi_in[i];
        dv     = dv_in[i];
        inv_dd = 1.0f / (dd_in[i] + EPS);  // hoisted: per-step div -> mul
    }

    float acc[STEPS];
#pragma unroll
    for (int t = 0; t < STEPS; ++t) {
        // s_star = s0 + max(0, v*T + v*dv*inv2)
        const float s_star = s0 + fmaxf(0.0f, fmaf(v * dv, inv2, v * T));
        const float q  = s_star * inv_dd;        // s_star / (dd + eps)
        const float r  = v * inv_vf;             // v / vf
        const float r2 = r * r;
        const float r4 = r2 * r2;
        const float ahat = A * fmaf(-q, q, 1.0f - r4);
        acc[t] = ahat;                           // recorded pre-update (scan semantics)
        v  = fmaf(ahat,  DT, v);
        dv = fmaf(ahat, -DT, dv);
    }

    const int g_of = tid >> 6;   // which group this thread's element is in
    const int l_of = tid & 63;   // lane within the group

    // Prologue: stage group 0 into buffer 0.
    if (g_of == 0) {
#pragma unroll
        for (int t = 0; t < STEPS; t += 2) {
            f32x2 w; w.x = acc[t]; w.y = acc[t + 1];
            *reinterpret_cast<f32x2*>(&lds[0][l_of * STEPS + t]) = w;
        }
    }
    __syncthreads();

    const long long total = (long long)n * STEPS;

#pragma unroll
    for (int g = 0; g < NGROUPS; ++g) {
        // Stage group g+1 into the other buffer (overlaps the store below).
        if (g + 1 < NGROUPS && g_of == g + 1) {
            const int nb = (g + 1) & 1;
#pragma unroll
            for (int t = 0; t < STEPS; t += 2) {
                f32x2 w; w.x = acc[t]; w.y = acc[t + 1];
                *reinterpret_cast<f32x2*>(&lds[nb][l_of * STEPS + t]) = w;
            }
        }

        // All 256 threads stream group g's buffer to global, coalesced.
        const long long gbase = (long long)(base + g * GROUP) * STEPS;
        if (gbase < total) {
            long long rem = total - gbase;
            int chunk = GROUP * STEPS;
            if (rem < chunk) chunk = (int)rem;
            const int nv = chunk >> 2;
            f32x4* __restrict__ outv      = reinterpret_cast<f32x4*>(out + gbase);
            const f32x4* __restrict__ ldv =
                reinterpret_cast<const f32x4*>(lds[g & 1]);
            for (int m = tid; m < nv; m += BLOCK) {
                __builtin_nontemporal_store(ldv[m], &outv[m]);
            }
            for (int k = (nv << 2) + tid; k < chunk; k += BLOCK) {
                out[gbase + k] = lds[g & 1][k];  // scalar tail (not hit at 1M)
            }
        }
        __syncthreads();
    }
}

} // namespace

extern "C" void kernel_launch(void* const* d_in, const int* in_sizes, int n_in,
                              void* d_out, int out_size, void* d_ws, size_t ws_size,
                              hipStream_t stream) {
    const float* vi = (const float*)d_in[0];
    const float* dv = (const float*)d_in[1];
    const float* dd = (const float*)d_in[2];
    const float* vf = (const float*)d_in[3];
    const float* A  = (const float*)d_in[4];
    const float* b  = (const float*)d_in[5];
    const float* s0 = (const float*)d_in[6];
    const float* T  = (const float*)d_in[7];
    float* out = (float*)d_out;

    const int n    = in_sizes[0];
    const int grid = (n + BLOCK - 1) / BLOCK;
    idm_forward<<<grid, BLOCK, 0, stream>>>(vi, dv, dd, vf, A, b, s0, T, out, n);
}

// Round 4
// 218.007 us; speedup vs baseline: 1.0460x; 1.0460x over previous
//
#include <hip/hip_runtime.h>

// IDM layer forward: 1M independent elements, 50 Euler steps each,
// output (BATCH, 50) f32 row-major. Write-BW-bound (200 MB out, 12 MB in).
//
// v3: ZERO barriers. Each wave owns a private 6400 B LDS buffer and
// processes its 64 elements in two 32-element halves:
//   stage half h (lanes h*32..h*32+31 write their acc[50] to LDS)
//   -> all 64 lanes stream the 6400 B contiguous chunk to global
//      with coalesced float4 stores (plain, not nontemporal).
// Wave-internal LDS ordering is compiler-handled (lgkmcnt); no
// __syncthreads anywhere -> waves free-run and pipeline naturally.
// LDS = 4 waves x 6400 B = 25,600 B/block -> 6 blocks/CU = 24 waves/CU.
// __launch_bounds__(256,5): VGPR cap 102 (need ~80 incl acc[50] -> no spill).

namespace {

constexpr int STEPS = 50;
constexpr int BLOCK = 256;
constexpr int HALF  = 32;                    // elements staged per round
constexpr float DT  = 0.1f;
constexpr float EPS = 1e-5f;

typedef float f32x4 __attribute__((ext_vector_type(4)));
typedef float f32x2 __attribute__((ext_vector_type(2)));

__global__ __launch_bounds__(BLOCK, 5) void idm_forward(
    const float* __restrict__ vi_in,
    const float* __restrict__ dv_in,
    const float* __restrict__ dd_in,
    const float* __restrict__ p_vf,
    const float* __restrict__ p_A,
    const float* __restrict__ p_b,
    const float* __restrict__ p_s0,
    const float* __restrict__ p_T,
    float* __restrict__ out,
    int n)
{
    __shared__ __align__(16) float lds[BLOCK / 64][HALF * STEPS];  // 4 x 6400 B

    const int tid  = threadIdx.x;
    const int wid  = tid >> 6;
    const int lane = tid & 63;
    const int i    = blockIdx.x * BLOCK + tid;

    // Scalar learned params (uniform -> s_load).
    const float vf = p_vf[0];
    const float A  = p_A[0];
    const float b  = p_b[0];
    const float s0 = p_s0[0];
    const float T  = p_T[0];
    const float inv2   = 1.0f / (2.0f * sqrtf(A * b));   // 1/(2*sqrt(A*b))
    const float inv_vf = 1.0f / vf;

    float v = 0.0f, dv = 0.0f, inv_dd = 1.0f;
    if (i < n) {
        v      = vi_in[i];
        dv     = dv_in[i];
        inv_dd = 1.0f / (dd_in[i] + EPS);  // hoisted: per-step div -> mul
    }

    float acc[STEPS];
#pragma unroll
    for (int t = 0; t < STEPS; ++t) {
        // s_star = s0 + max(0, v*T + v*dv/(2*sqrt(A*b)))
        const float s_star = s0 + fmaxf(0.0f, fmaf(v * dv, inv2, v * T));
        const float q  = s_star * inv_dd;        // s_star / (dd + eps)
        const float r  = v * inv_vf;             // v / vf
        const float r2 = r * r;
        const float r4 = r2 * r2;
        const float ahat = A * fmaf(-q, q, 1.0f - r4);
        acc[t] = ahat;                           // recorded pre-update (scan semantics)
        v  = fmaf(ahat,  DT, v);
        dv = fmaf(ahat, -DT, dv);
    }

    float* wbuf = lds[wid];
    const long long total = (long long)n * STEPS;
    // This wave's 64 elements start at element (blockIdx*256 + wid*64).
    const long long ebase = (long long)blockIdx.x * BLOCK + (wid << 6);

#pragma unroll
    for (int h = 0; h < 2; ++h) {
        // Stage: lanes [h*32, h*32+32) write their 50 acc values (b64 writes,
        // 8B-aligned since t even). Other lanes idle; tiny phase.
        if ((lane >> 5) == h) {
            const int l = lane & 31;
#pragma unroll
            for (int t = 0; t < STEPS; t += 2) {
                f32x2 w; w.x = acc[t]; w.y = acc[t + 1];
                *reinterpret_cast<f32x2*>(&wbuf[l * STEPS + t]) = w;
            }
        }

        // Stream the 6400 B contiguous chunk (32 elems x 50 steps) to global.
        const long long gbase = (ebase + h * HALF) * STEPS;
        if (gbase < total) {
            long long rem = total - gbase;
            int chunk = HALF * STEPS;                   // 1600 floats
            if (rem < chunk) chunk = (int)rem;
            const int nv = chunk >> 2;                  // 400 float4
            f32x4* __restrict__ outv      = reinterpret_cast<f32x4*>(out + gbase);
            const f32x4* __restrict__ ldv = reinterpret_cast<const f32x4*>(wbuf);
            for (int m = lane; m < nv; m += 64) {
                outv[m] = ldv[m];
            }
            for (int k = (nv << 2) + lane; k < chunk; k += 64) {
                out[gbase + k] = wbuf[k];               // scalar tail (not hit at 1M)
            }
        }
        // No barrier: next half's ds_writes are ordered after this half's
        // ds_reads by the wave's in-order LDS pipe / compiler lgkmcnt.
    }
}

} // namespace

extern "C" void kernel_launch(void* const* d_in, const int* in_sizes, int n_in,
                              void* d_out, int out_size, void* d_ws, size_t ws_size,
                              hipStream_t stream) {
    const float* vi = (const float*)d_in[0];
    const float* dv = (const float*)d_in[1];
    const float* dd = (const float*)d_in[2];
    const float* vf = (const float*)d_in[3];
    const float* A  = (const float*)d_in[4];
    const float* b  = (const float*)d_in[5];
    const float* s0 = (const float*)d_in[6];
    const float* T  = (const float*)d_in[7];
    float* out = (float*)d_out;

    const int n    = in_sizes[0];
    const int grid = (n + BLOCK - 1) / BLOCK;
    idm_forward<<<grid, BLOCK, 0, stream>>>(vi, dv, dd, vf, A, b, s0, T, out, n);
}